// Round 2
// baseline (837.976 us; speedup 1.0000x reference)
//
#include <hip/hip_runtime.h>
#include <hip/hip_bf16.h>

// Round 7 (= Round 6 resubmit; previous bench died on container infra):
// (1) O-projection GEMM single-pass f16 (its output is never re-quantized,
// so the hi/lo correction passes are unnecessary there);
// (2) Q/K/V GEMMs fused into one launch (1536 blocks -> ~3 blocks/CU instead
// of 2, recovers inter-block overlap of the barrier drain);
// (3) attention: T14 async-STAGE split (issue next K/V tile's global loads
// into registers before compute, ds_write after the next barrier).

typedef _Float16 f16;
typedef _Float16 f16x8 __attribute__((ext_vector_type(8)));
typedef float f32x4 __attribute__((ext_vector_type(4)));

static constexpr int Bd = 2, Sd = 2048, NH = 32, HD = 64, HID = 2048;
static constexpr int Md = Bd * Sd;   // 4096
static constexpr int LSTR = 72;      // LDS row stride (f16) for attn tiles

// ---------------- FP4 fake-quant (E2M1, block-16 absmax) ----------------
__device__ __forceinline__ float fp4_grid_round(float ay) {
  if (ay <= 0.25f) return 0.0f;
  if (ay <= 0.75f) return 0.5f;
  if (ay <= 1.25f) return 1.0f;
  if (ay <= 1.75f) return 1.5f;
  if (ay <= 2.5f)  return 2.0f;
  if (ay <= 3.5f)  return 3.0f;
  if (ay <= 5.0f)  return 4.0f;
  return 6.0f;
}

__global__ __launch_bounds__(256) void quant_fp4_split_kernel(const float* __restrict__ in,
                                                              f16* __restrict__ hi,
                                                              f16* __restrict__ lo, int n4) {
  int t = blockIdx.x * 256 + threadIdx.x;
  if (t >= n4) return;
  float v[4];
#pragma unroll
  for (int i = 0; i < 4; ++i) v[i] = in[4 * t + i];
  float a = fmaxf(fmaxf(fabsf(v[0]), fabsf(v[1])), fmaxf(fabsf(v[2]), fabsf(v[3])));
  a = fmaxf(a, __shfl_xor(a, 1));
  a = fmaxf(a, __shfl_xor(a, 2));
  float scale = (a == 0.0f) ? 1.0f : (a / 6.0f);
#pragma unroll
  for (int i = 0; i < 4; ++i) {
    float y = v[i] / scale;
    float g = fp4_grid_round(fabsf(y));
    float qv = copysignf(g * scale, y);
    f16 h = (f16)qv;
    hi[4 * t + i] = h;
    lo[4 * t + i] = (f16)(qv - (float)h);
  }
}

// ---------------- async global->LDS helper ----------------------------------
__device__ __forceinline__ void gl2lds16(const f16* g, f16* l) {
  __builtin_amdgcn_global_load_lds(
      (const __attribute__((address_space(1))) unsigned int*)g,
      (__attribute__((address_space(3))) unsigned int*)l, 16, 0, 0);
}

// ---------------- split GEMM core macro-parts -------------------------------
// 256 thr = 4 waves (2x2), 128x128 tile, BK=32. C ≈ Ah*Bh + Ah*Bl + Al*Bh.

// K-loop shared by split-GEMM variants (defines acc[4][4]).
#define GEMM128_BODY(Ah, Al, Bh, Bl, Kk, JN)                                   \
  __shared__ f16 sAh[128 * 32];                                                \
  __shared__ f16 sAl[128 * 32];                                                \
  __shared__ f16 sBh[128 * 32];                                                \
  __shared__ f16 sBl[128 * 32];                                                \
  const int tid = threadIdx.x;                                                 \
  const int w = tid >> 6, lane = tid & 63;                                     \
  const int wm = w & 1, wn = w >> 1;                                           \
  const int quad = lane >> 4, n16 = lane & 15;                                 \
  const int im = blockIdx.x, jn = (JN);                                        \
  const int srow = lane >> 2;                                                  \
  const int schk = (lane & 3) * 8;                                             \
  const size_t arow0 = (size_t)(im * 128) * Kk;                                \
  const size_t brow0 = (size_t)(jn * 128) * Kk;                                \
  f32x4 acc[4][4];                                                             \
  _Pragma("unroll") for (int i = 0; i < 4; ++i)                                \
      _Pragma("unroll") for (int j = 0; j < 4; ++j)                            \
          acc[i][j] = f32x4{0.f, 0.f, 0.f, 0.f};                               \
  for (int kk = 0; kk < Kk; kk += 32) {                                        \
    __syncthreads();                                                           \
    _Pragma("unroll") for (int g = 0; g < 2; ++g) {                            \
      int r = g * 64 + w * 16;                                                 \
      int lb = r * 32;                                                         \
      size_t go = (size_t)(r + srow) * Kk + kk + schk;                         \
      gl2lds16(Ah + arow0 + go, &sAh[lb]);                                     \
      gl2lds16(Al + arow0 + go, &sAl[lb]);                                     \
      gl2lds16(Bh + brow0 + go, &sBh[lb]);                                     \
      gl2lds16(Bl + brow0 + go, &sBl[lb]);                                     \
    }                                                                          \
    __syncthreads();                                                           \
    f16x8 ah[4], al[4], bh[4], bl[4];                                          \
    _Pragma("unroll") for (int t = 0; t < 4; ++t) {                            \
      int ao = (wm * 64 + t * 16 + n16) * 32 + quad * 8;                       \
      int bo = (wn * 64 + t * 16 + n16) * 32 + quad * 8;                       \
      ah[t] = *(const f16x8*)&sAh[ao];                                         \
      al[t] = *(const f16x8*)&sAl[ao];                                         \
      bh[t] = *(const f16x8*)&sBh[bo];                                         \
      bl[t] = *(const f16x8*)&sBl[bo];                                         \
    }                                                                          \
    _Pragma("unroll") for (int ti = 0; ti < 4; ++ti)                           \
        _Pragma("unroll") for (int tj = 0; tj < 4; ++tj) {                     \
      acc[ti][tj] = __builtin_amdgcn_mfma_f32_16x16x32_f16(ah[ti], bh[tj],     \
                                                           acc[ti][tj], 0, 0, 0); \
      acc[ti][tj] = __builtin_amdgcn_mfma_f32_16x16x32_f16(ah[ti], bl[tj],     \
                                                           acc[ti][tj], 0, 0, 0); \
      acc[ti][tj] = __builtin_amdgcn_mfma_f32_16x16x32_f16(al[ti], bh[tj],     \
                                                           acc[ti][tj], 0, 0, 0); \
    }                                                                          \
  }

// Fused QKV GEMM: blockIdx.y in [0,16)=Q (RoPE epi), [16,32)=K (RoPE epi),
// [32,48)=V (plain fp32 epi). One launch -> 1536 blocks (~3/CU occupancy).
__global__ __launch_bounds__(256) void gemm128_qkv(
    const f16* __restrict__ Xh, const f16* __restrict__ Xl,
    const f16* __restrict__ Wqh, const f16* __restrict__ Wql,
    const f16* __restrict__ Wkh, const f16* __restrict__ Wkl,
    const f16* __restrict__ Wvh, const f16* __restrict__ Wvl,
    f16* __restrict__ Qoh, f16* __restrict__ Qol,
    f16* __restrict__ Koh, f16* __restrict__ Kol,
    float* __restrict__ Vo) {
  const int sel = blockIdx.y >> 4;  // 0=Q 1=K 2=V (block-uniform)
  const f16* Bh = (sel == 0) ? Wqh : (sel == 1) ? Wkh : Wvh;
  const f16* Bl = (sel == 0) ? Wql : (sel == 1) ? Wkl : Wvl;
  GEMM128_BODY(Xh, Xl, Bh, Bl, HID, ((int)blockIdx.y & 15))
  if (sel == 2) {
    // plain fp32 epilogue into Vo [M, HID]
#pragma unroll
    for (int ti = 0; ti < 4; ++ti)
#pragma unroll
      for (int tj = 0; tj < 4; ++tj) {
        size_t row = (size_t)(im * 128 + wm * 64 + ti * 16 + quad * 4);
        size_t col = jn * 128 + wn * 64 + tj * 16 + n16;
#pragma unroll
        for (int r = 0; r < 4; ++r)
          Vo[(row + r) * HID + col] = acc[ti][tj][r];
      }
  } else {
    // fused RoPE + qscale + f16 hi/lo split, head-major [head][s][d]
    f16* Oh = sel ? Koh : Qoh;
    f16* Ol = sel ? Kol : Qol;
    const float qscale = sel ? 1.0f : 0.125f;
    const int hidx = (jn * 128 + wn * 64) >> 6;  // 0..31
    const int b = im >> 4;                       // im*128 / 2048
    const size_t obase = (size_t)(b * 32 + hidx) * Sd * 64;
    const float inv0 = expf(-0.2878231366242557f * (float)n16);
    const float inv1 = expf(-0.2878231366242557f * (float)(16 + n16));
#pragma unroll
    for (int ti = 0; ti < 4; ++ti)
#pragma unroll
      for (int r = 0; r < 4; ++r) {
        int row = im * 128 + wm * 64 + ti * 16 + quad * 4 + r;
        int s = row & (Sd - 1);
#pragma unroll
        for (int tjp = 0; tjp < 2; ++tjp) {
          float inv = tjp ? inv1 : inv0;
          float sn, cs;
          sincosf((float)s * inv, &sn, &cs);
          float x1 = acc[ti][tjp][r] * qscale;
          float x2 = acc[ti][tjp + 2][r] * qscale;
          float o1 = x1 * cs - x2 * sn;
          float o2 = x2 * cs + x1 * sn;
          size_t i1 = obase + (size_t)s * 64 + tjp * 16 + n16;
          f16 hh;
          hh = (f16)o1; Oh[i1] = hh;      Ol[i1] = (f16)(o1 - (float)hh);
          hh = (f16)o2; Oh[i1 + 32] = hh; Ol[i1 + 32] = (f16)(o2 - (float)hh);
        }
      }
  }
}

// Single-pass f16 GEMM for the output projection. Its result is never
// re-quantized, so f16 representation error (~1e-4 abs on out) is fine.
__global__ __launch_bounds__(256) void gemm128_h(const f16* __restrict__ Ah,
                                                 const f16* __restrict__ Bh,
                                                 float* __restrict__ C,
                                                 int Nn, int Kk) {
  __shared__ f16 sAh[128 * 32];
  __shared__ f16 sBh[128 * 32];
  const int tid = threadIdx.x;
  const int w = tid >> 6, lane = tid & 63;
  const int wm = w & 1, wn = w >> 1;
  const int quad = lane >> 4, n16 = lane & 15;
  const int im = blockIdx.x, jn = blockIdx.y;
  const int srow = lane >> 2;
  const int schk = (lane & 3) * 8;
  const size_t arow0 = (size_t)(im * 128) * Kk;
  const size_t brow0 = (size_t)(jn * 128) * Kk;
  f32x4 acc[4][4];
#pragma unroll
  for (int i = 0; i < 4; ++i)
#pragma unroll
    for (int j = 0; j < 4; ++j) acc[i][j] = f32x4{0.f, 0.f, 0.f, 0.f};
  for (int kk = 0; kk < Kk; kk += 32) {
    __syncthreads();
#pragma unroll
    for (int g = 0; g < 2; ++g) {
      int r = g * 64 + w * 16;
      int lb = r * 32;
      size_t go = (size_t)(r + srow) * Kk + kk + schk;
      gl2lds16(Ah + arow0 + go, &sAh[lb]);
      gl2lds16(Bh + brow0 + go, &sBh[lb]);
    }
    __syncthreads();
    f16x8 ah[4], bh[4];
#pragma unroll
    for (int t = 0; t < 4; ++t) {
      int ao = (wm * 64 + t * 16 + n16) * 32 + quad * 8;
      int bo = (wn * 64 + t * 16 + n16) * 32 + quad * 8;
      ah[t] = *(const f16x8*)&sAh[ao];
      bh[t] = *(const f16x8*)&sBh[bo];
    }
#pragma unroll
    for (int ti = 0; ti < 4; ++ti)
#pragma unroll
      for (int tj = 0; tj < 4; ++tj)
        acc[ti][tj] = __builtin_amdgcn_mfma_f32_16x16x32_f16(ah[ti], bh[tj],
                                                             acc[ti][tj], 0, 0, 0);
  }
#pragma unroll
  for (int ti = 0; ti < 4; ++ti)
#pragma unroll
    for (int tj = 0; tj < 4; ++tj) {
      size_t row = (size_t)(im * 128 + wm * 64 + ti * 16 + quad * 4);
      size_t col = jn * 128 + wn * 64 + tj * 16 + n16;
#pragma unroll
      for (int r = 0; r < 4; ++r)
        C[(row + r) * Nn + col] = acc[ti][tj][r];
    }
}

// ---------------- V transpose + split: Vt[head][d][s] -----------------------
__global__ __launch_bounds__(256) void v_split_t_kernel(const float* __restrict__ V,
                                                        f16* __restrict__ Vth,
                                                        f16* __restrict__ Vtl) {
  __shared__ float tile[64][65];
  int head = blockIdx.x;
  int st = blockIdx.y;
  int b = head >> 5, h = head & 31;
  int tid = threadIdx.x;
  int r = tid >> 2, c4 = (tid & 3) * 16;
  const float* vp = V + (((size_t)(b * Sd + st * 64 + r)) * NH + h) * 64 + c4;
#pragma unroll
  for (int i = 0; i < 16; i += 4) {
    float4 v = *(const float4*)(vp + i);
    tile[r][c4 + i] = v.x; tile[r][c4 + i + 1] = v.y;
    tile[r][c4 + i + 2] = v.z; tile[r][c4 + i + 3] = v.w;
  }
  __syncthreads();
  int d = tid >> 2, s0 = (tid & 3) * 16;
  f16x8 hv[2], lv[2];
#pragma unroll
  for (int g = 0; g < 2; ++g)
#pragma unroll
    for (int i = 0; i < 8; ++i) {
      float v = tile[s0 + g * 8 + i][d];
      f16 hh = (f16)v;
      hv[g][i] = hh;
      lv[g][i] = (f16)(v - (float)hh);
    }
  size_t outb = (size_t)head * 64 * Sd + (size_t)d * Sd + st * 64 + s0;
  *(f16x8*)(Vth + outb) = hv[0];
  *(f16x8*)(Vth + outb + 8) = hv[1];
  *(f16x8*)(Vtl + outb) = lv[0];
  *(f16x8*)(Vtl + outb + 8) = lv[1];
}

// ---------------- MFMA flash attention, 128 q-rows per block ----------------
// 4 waves x 32 q-rows; K/V tiles of 64; f16 hi/lo split everywhere.
// T14: next tile's global loads issued into registers before compute.
__global__ __launch_bounds__(256) void attn_mfma_kernel(
    const f16* __restrict__ Qh, const f16* __restrict__ Ql,
    const f16* __restrict__ Kh, const f16* __restrict__ Kl,
    const f16* __restrict__ Vth, const f16* __restrict__ Vtl,
    float* __restrict__ O) {
  __shared__ f16 lds_kh[64 * LSTR];
  __shared__ f16 lds_kl[64 * LSTR];
  __shared__ f16 lds_vh[64 * LSTR];
  __shared__ f16 lds_vl[64 * LSTR];
  __shared__ f16 lds_ph[128 * LSTR];   // 4 waves * 32 rows
  __shared__ f16 lds_pl[128 * LSTR];

  const int tid = threadIdx.x;
  const int wave = tid >> 6, lane = tid & 63;
  const int quad = lane >> 4, n16 = lane & 15;
  const int head = blockIdx.x;
  const int qt = 15 - blockIdx.y;        // longest blocks first
  const int b = head >> 5, h = head & 31;

  const size_t hbase = (size_t)head * Sd * 64;
  const size_t vbase = (size_t)head * 64 * Sd;
  const int qrow_w = qt * 128 + wave * 32;

  // persistent Q fragments (A-layout), 2 row-tiles of 16
  f16x8 qah[2][2], qal[2][2];
#pragma unroll
  for (int ti = 0; ti < 2; ++ti) {
    const f16* qp = Qh + hbase + (size_t)(qrow_w + ti * 16 + n16) * 64 + quad * 8;
    const f16* qp2 = Ql + hbase + (size_t)(qrow_w + ti * 16 + n16) * 64 + quad * 8;
    qah[ti][0] = *(const f16x8*)(qp);
    qah[ti][1] = *(const f16x8*)(qp + 32);
    qal[ti][0] = *(const f16x8*)(qp2);
    qal[ti][1] = *(const f16x8*)(qp2 + 32);
  }

  f32x4 acco[2][4];
#pragma unroll
  for (int ti = 0; ti < 2; ++ti)
#pragma unroll
    for (int t = 0; t < 4; ++t) acco[ti][t] = f32x4{0.f, 0.f, 0.f, 0.f};
  float mrow[2][4], lrow[2][4];
#pragma unroll
  for (int ti = 0; ti < 2; ++ti)
#pragma unroll
    for (int r = 0; r < 4; ++r) { mrow[ti][r] = -INFINITY; lrow[ti][r] = 0.f; }

  const int sr = tid >> 2, ss = (tid & 3) * 16;
  const int nkt = 2 * qt + 2;

  // staging source pointers (advance by constants per kt)
  const f16* pk  = Kh  + hbase + (size_t)sr * 64 + ss;
  const f16* pkl = Kl  + hbase + (size_t)sr * 64 + ss;
  const f16* pv  = Vth + vbase + (size_t)sr * Sd + ss;
  const f16* pvl = Vtl + vbase + (size_t)sr * Sd + ss;

  f16x8 r0, r1, r2, r3, r4, r5, r6, r7;
#define ISSUE_KV(ktv) {                                                        \
    const f16* gk  = pk  + (size_t)(ktv) * (64 * 64);                          \
    const f16* gkl = pkl + (size_t)(ktv) * (64 * 64);                          \
    const f16* gv  = pv  + (ktv) * 64;                                         \
    const f16* gvl = pvl + (ktv) * 64;                                         \
    r0 = *(const f16x8*)(gk);      r1 = *(const f16x8*)(gk + 8);               \
    r2 = *(const f16x8*)(gkl);     r3 = *(const f16x8*)(gkl + 8);              \
    r4 = *(const f16x8*)(gv);      r5 = *(const f16x8*)(gv + 8);               \
    r6 = *(const f16x8*)(gvl);     r7 = *(const f16x8*)(gvl + 8); }

  ISSUE_KV(0);

  for (int kt = 0; kt < nkt; ++kt) {
    __syncthreads();
    {
      int la = sr * LSTR + ss;
      *(f16x8*)&lds_kh[la] = r0; *(f16x8*)&lds_kh[la + 8] = r1;
      *(f16x8*)&lds_kl[la] = r2; *(f16x8*)&lds_kl[la + 8] = r3;
      *(f16x8*)&lds_vh[la] = r4; *(f16x8*)&lds_vh[la + 8] = r5;
      *(f16x8*)&lds_vl[la] = r6; *(f16x8*)&lds_vl[la + 8] = r7;
    }
    if (kt + 1 < nkt) ISSUE_KV(kt + 1);   // fly under this tile's compute
    __syncthreads();

    if (kt * 64 > qrow_w + 31) continue;  // fully-masked for this wave

    // S = Q*K^T: 32 q-rows x 64 k-cols per wave
    f32x4 sacc[2][4];
#pragma unroll
    for (int ti = 0; ti < 2; ++ti)
#pragma unroll
      for (int t = 0; t < 4; ++t) sacc[ti][t] = f32x4{0.f, 0.f, 0.f, 0.f};
#pragma unroll
    for (int t = 0; t < 4; ++t) {
      int off = (t * 16 + n16) * LSTR + quad * 8;
      f16x8 kb0h = *(const f16x8*)&lds_kh[off];
      f16x8 kb1h = *(const f16x8*)&lds_kh[off + 32];
      f16x8 kb0l = *(const f16x8*)&lds_kl[off];
      f16x8 kb1l = *(const f16x8*)&lds_kl[off + 32];
#pragma unroll
      for (int ti = 0; ti < 2; ++ti) {
        sacc[ti][t] = __builtin_amdgcn_mfma_f32_16x16x32_f16(qah[ti][0], kb0h, sacc[ti][t], 0, 0, 0);
        sacc[ti][t] = __builtin_amdgcn_mfma_f32_16x16x32_f16(qah[ti][1], kb1h, sacc[ti][t], 0, 0, 0);
        sacc[ti][t] = __builtin_amdgcn_mfma_f32_16x16x32_f16(qah[ti][0], kb0l, sacc[ti][t], 0, 0, 0);
        sacc[ti][t] = __builtin_amdgcn_mfma_f32_16x16x32_f16(qah[ti][1], kb1l, sacc[ti][t], 0, 0, 0);
        sacc[ti][t] = __builtin_amdgcn_mfma_f32_16x16x32_f16(qal[ti][0], kb0h, sacc[ti][t], 0, 0, 0);
        sacc[ti][t] = __builtin_amdgcn_mfma_f32_16x16x32_f16(qal[ti][1], kb1h, sacc[ti][t], 0, 0, 0);
      }
    }

    if (kt * 64 + 63 > qrow_w) {  // partial mask
#pragma unroll
      for (int ti = 0; ti < 2; ++ti)
#pragma unroll
        for (int t = 0; t < 4; ++t)
#pragma unroll
          for (int r = 0; r < 4; ++r) {
            int kc = kt * 64 + t * 16 + n16;
            int qr = qrow_w + ti * 16 + quad * 4 + r;
            if (kc > qr) sacc[ti][t][r] = -INFINITY;
          }
    }

    // online softmax per row-tile
#pragma unroll
    for (int ti = 0; ti < 2; ++ti) {
      float mt[4];
#pragma unroll
      for (int r = 0; r < 4; ++r)
        mt[r] = fmaxf(fmaxf(sacc[ti][0][r], sacc[ti][1][r]),
                      fmaxf(sacc[ti][2][r], sacc[ti][3][r]));
#pragma unroll
      for (int i = 1; i < 16; i <<= 1)
#pragma unroll
        for (int r = 0; r < 4; ++r)
          mt[r] = fmaxf(mt[r], __shfl_xor(mt[r], i));
      float alpha[4], psum[4];
#pragma unroll
      for (int r = 0; r < 4; ++r) {
        float mn = fmaxf(mrow[ti][r], mt[r]);
        alpha[r] = __expf(mrow[ti][r] - mn);
        mrow[ti][r] = mn;
        psum[r] = 0.f;
      }
#pragma unroll
      for (int t = 0; t < 4; ++t)
#pragma unroll
        for (int r = 0; r < 4; ++r) {
          float p = __expf(sacc[ti][t][r] - mrow[ti][r]);
          psum[r] += p;
          f16 ph = (f16)p;
          int addr = (wave * 32 + ti * 16 + quad * 4 + r) * LSTR + t * 16 + n16;
          lds_ph[addr] = ph;
          lds_pl[addr] = (f16)(p - (float)ph);
        }
#pragma unroll
      for (int i = 1; i < 16; i <<= 1)
#pragma unroll
        for (int r = 0; r < 4; ++r)
          psum[r] += __shfl_xor(psum[r], i);
#pragma unroll
      for (int r = 0; r < 4; ++r) lrow[ti][r] = lrow[ti][r] * alpha[r] + psum[r];
#pragma unroll
      for (int t = 0; t < 4; ++t)
#pragma unroll
        for (int r = 0; r < 4; ++r) acco[ti][t][r] *= alpha[r];
    }

    __asm__ volatile("s_waitcnt lgkmcnt(0)" ::: "memory");

    // O += P * V
    f16x8 pa0h[2], pa1h[2], pa0l[2], pa1l[2];
#pragma unroll
    for (int ti = 0; ti < 2; ++ti) {
      int pbase = (wave * 32 + ti * 16 + n16) * LSTR + quad * 8;
      pa0h[ti] = *(const f16x8*)&lds_ph[pbase];
      pa1h[ti] = *(const f16x8*)&lds_ph[pbase + 32];
      pa0l[ti] = *(const f16x8*)&lds_pl[pbase];
      pa1l[ti] = *(const f16x8*)&lds_pl[pbase + 32];
    }
#pragma unroll
    for (int t = 0; t < 4; ++t) {
      int off = (t * 16 + n16) * LSTR + quad * 8;
      f16x8 vb0h = *(const f16x8*)&lds_vh[off];
      f16x8 vb1h = *(const f16x8*)&lds_vh[off + 32];
      f16x8 vb0l = *(const f16x8*)&lds_vl[off];
      f16x8 vb1l = *(const f16x8*)&lds_vl[off + 32];
#pragma unroll
      for (int ti = 0; ti < 2; ++ti) {
        acco[ti][t] = __builtin_amdgcn_mfma_f32_16x16x32_f16(pa0h[ti], vb0h, acco[ti][t], 0, 0, 0);
        acco[ti][t] = __builtin_amdgcn_mfma_f32_16x16x32_f16(pa1h[ti], vb1h, acco[ti][t], 0, 0, 0);
        acco[ti][t] = __builtin_amdgcn_mfma_f32_16x16x32_f16(pa0h[ti], vb0l, acco[ti][t], 0, 0, 0);
        acco[ti][t] = __builtin_amdgcn_mfma_f32_16x16x32_f16(pa1h[ti], vb1l, acco[ti][t], 0, 0, 0);
        acco[ti][t] = __builtin_amdgcn_mfma_f32_16x16x32_f16(pa0l[ti], vb0h, acco[ti][t], 0, 0, 0);
        acco[ti][t] = __builtin_amdgcn_mfma_f32_16x16x32_f16(pa1l[ti], vb1h, acco[ti][t], 0, 0, 0);
      }
    }
  }
#undef ISSUE_KV

  // epilogue: O in [b,s,h,d] fp32
#pragma unroll
  for (int ti = 0; ti < 2; ++ti) {
#pragma unroll
    for (int r = 0; r < 4; ++r) {
      float rl = 1.f / lrow[ti][r];
      int qr = qrow_w + ti * 16 + quad * 4 + r;
#pragma unroll
      for (int t = 0; t < 4; ++t)
        O[(((size_t)(b * Sd + qr)) * NH + h) * 64 + t * 16 + n16] = acco[ti][t][r] * rl;
    }
  }
}

// ---------------- launch ----------------------------------------------------
extern "C" void kernel_launch(void* const* d_in, const int* in_sizes, int n_in,
                              void* d_out, int out_size, void* d_ws, size_t ws_size,
                              hipStream_t stream) {
  (void)in_sizes; (void)n_in; (void)out_size; (void)ws_size;
  const float* x  = (const float*)d_in[0];
  const float* Wq = (const float*)d_in[1];
  const float* Wk = (const float*)d_in[2];
  const float* Wv = (const float*)d_in[3];
  const float* Wo = (const float*)d_in[4];
  float* out = (float*)d_out;

  const size_t NX = (size_t)Md * HID;   // 8,388,608
  const size_t NW = (size_t)HID * HID;  // 4,194,304

  char* w = (char*)d_ws;
  size_t off = 0;
  auto alloc = [&](size_t bytes) { void* p = w + off; off += (bytes + 255) & ~(size_t)255; return p; };
  f16* xh  = (f16*)alloc(NX * 2);
  f16* xl  = (f16*)alloc(NX * 2);
  f16* wqh = (f16*)alloc(NW * 2);
  f16* wql = (f16*)alloc(NW * 2);
  f16* wkh = (f16*)alloc(NW * 2);
  f16* wkl = (f16*)alloc(NW * 2);
  f16* wvh = (f16*)alloc(NW * 2);
  f16* wvl = (f16*)alloc(NW * 2);
  f16* woh = (f16*)alloc(NW * 2);
  f16* wol = (f16*)alloc(NW * 2);
  float* vb = (float*)alloc(NX * 4);
  f16* qhs = (f16*)alloc(NX * 2);
  f16* qls = (f16*)alloc(NX * 2);
  f16* khs = (f16*)alloc(NX * 2);
  f16* kls = (f16*)alloc(NX * 2);
  // aliases (dead-after analysis):
  f16* vth = xh;            // x splits dead after QKV gemm; vth/vtl live for attn
  f16* vtl = xl;
  float* ob = (float*)wqh;  // wq/wk splits dead after QKV gemm (4*NW*2 = NX*4 B)
  f16* oh = qhs;            // q splits dead after attn
  f16* ol = qls;

  const int nx4 = (int)(NX / 4);
  const int nw4 = (int)(NW / 4);
  quant_fp4_split_kernel<<<nx4 / 256, 256, 0, stream>>>(x, xh, xl, nx4);
  quant_fp4_split_kernel<<<nw4 / 256, 256, 0, stream>>>(Wq, wqh, wql, nw4);
  quant_fp4_split_kernel<<<nw4 / 256, 256, 0, stream>>>(Wk, wkh, wkl, nw4);
  quant_fp4_split_kernel<<<nw4 / 256, 256, 0, stream>>>(Wv, wvh, wvl, nw4);
  quant_fp4_split_kernel<<<nw4 / 256, 256, 0, stream>>>(Wo, woh, wol, nw4);

  // fused Q/K/V projection GEMM: grid (32, 48)
  gemm128_qkv<<<dim3(Md / 128, 48), 256, 0, stream>>>(
      xh, xl, wqh, wql, wkh, wkl, wvh, wvl, qhs, qls, khs, kls, vb);

  v_split_t_kernel<<<dim3(64, 32), 256, 0, stream>>>(vb, vth, vtl);

  attn_mfma_kernel<<<dim3(64, 16), 256, 0, stream>>>(qhs, qls, khs, kls, vth, vtl, ob);

  quant_fp4_split_kernel<<<nx4 / 256, 256, 0, stream>>>(ob, oh, ol, nx4);
  // single-pass f16 output projection (result never re-quantized)
  gemm128_h<<<dim3(Md / 128, HID / 128), 256, 0, stream>>>(oh, woh, out, HID, HID);
}

// Round 3
// 716.062 us; speedup vs baseline: 1.1703x; 1.1703x over previous
//
#include <hip/hip_runtime.h>
#include <hip/hip_bf16.h>

// Round 8: attention-only changes (GEMMs at their 2-phase structural ceiling,
// 928 TF effective, left untouched):
// (1) true T14: in-loop barriers become lgkmcnt(0)-only asm barriers, so the
//     register prefetch of tile kt+1 stays in flight across the barrier and
//     drains under compute (round-7's __syncthreads drained vmcnt(0) at the
//     barrier, defeating the prefetch);
// (2) drop P-lo correction (P in (0,1], f16 rel err 2^-11 << fp4 flip scale):
//     PV 6->4 MFMA, lds_pl eliminated;
// (3) P stride 68 (136B: conflict-free spread) + smaller LDS (54272 B) ->
//     3 blocks/CU.

typedef _Float16 f16;
typedef _Float16 f16x8 __attribute__((ext_vector_type(8)));
typedef float f32x4 __attribute__((ext_vector_type(4)));

static constexpr int Bd = 2, Sd = 2048, NH = 32, HD = 64, HID = 2048;
static constexpr int Md = Bd * Sd;   // 4096
static constexpr int LSTR = 72;      // LDS row stride (f16) for K/V attn tiles
static constexpr int PSTR = 68;      // LDS row stride (f16) for P tile

// ---------------- FP4 fake-quant (E2M1, block-16 absmax) ----------------
__device__ __forceinline__ float fp4_grid_round(float ay) {
  if (ay <= 0.25f) return 0.0f;
  if (ay <= 0.75f) return 0.5f;
  if (ay <= 1.25f) return 1.0f;
  if (ay <= 1.75f) return 1.5f;
  if (ay <= 2.5f)  return 2.0f;
  if (ay <= 3.5f)  return 3.0f;
  if (ay <= 5.0f)  return 4.0f;
  return 6.0f;
}

__global__ __launch_bounds__(256) void quant_fp4_split_kernel(const float* __restrict__ in,
                                                              f16* __restrict__ hi,
                                                              f16* __restrict__ lo, int n4) {
  int t = blockIdx.x * 256 + threadIdx.x;
  if (t >= n4) return;
  float v[4];
#pragma unroll
  for (int i = 0; i < 4; ++i) v[i] = in[4 * t + i];
  float a = fmaxf(fmaxf(fabsf(v[0]), fabsf(v[1])), fmaxf(fabsf(v[2]), fabsf(v[3])));
  a = fmaxf(a, __shfl_xor(a, 1));
  a = fmaxf(a, __shfl_xor(a, 2));
  float scale = (a == 0.0f) ? 1.0f : (a / 6.0f);
#pragma unroll
  for (int i = 0; i < 4; ++i) {
    float y = v[i] / scale;
    float g = fp4_grid_round(fabsf(y));
    float qv = copysignf(g * scale, y);
    f16 h = (f16)qv;
    hi[4 * t + i] = h;
    lo[4 * t + i] = (f16)(qv - (float)h);
  }
}

// ---------------- async global->LDS helper ----------------------------------
__device__ __forceinline__ void gl2lds16(const f16* g, f16* l) {
  __builtin_amdgcn_global_load_lds(
      (const __attribute__((address_space(1))) unsigned int*)g,
      (__attribute__((address_space(3))) unsigned int*)l, 16, 0, 0);
}

// ---------------- split GEMM core macro-parts -------------------------------
// 256 thr = 4 waves (2x2), 128x128 tile, BK=32. C ≈ Ah*Bh + Ah*Bl + Al*Bh.

// K-loop shared by split-GEMM variants (defines acc[4][4]).
#define GEMM128_BODY(Ah, Al, Bh, Bl, Kk, JN)                                   \
  __shared__ f16 sAh[128 * 32];                                                \
  __shared__ f16 sAl[128 * 32];                                                \
  __shared__ f16 sBh[128 * 32];                                                \
  __shared__ f16 sBl[128 * 32];                                                \
  const int tid = threadIdx.x;                                                 \
  const int w = tid >> 6, lane = tid & 63;                                     \
  const int wm = w & 1, wn = w >> 1;                                           \
  const int quad = lane >> 4, n16 = lane & 15;                                 \
  const int im = blockIdx.x, jn = (JN);                                        \
  const int srow = lane >> 2;                                                  \
  const int schk = (lane & 3) * 8;                                             \
  const size_t arow0 = (size_t)(im * 128) * Kk;                                \
  const size_t brow0 = (size_t)(jn * 128) * Kk;                                \
  f32x4 acc[4][4];                                                             \
  _Pragma("unroll") for (int i = 0; i < 4; ++i)                                \
      _Pragma("unroll") for (int j = 0; j < 4; ++j)                            \
          acc[i][j] = f32x4{0.f, 0.f, 0.f, 0.f};                               \
  for (int kk = 0; kk < Kk; kk += 32) {                                        \
    __syncthreads();                                                           \
    _Pragma("unroll") for (int g = 0; g < 2; ++g) {                            \
      int r = g * 64 + w * 16;                                                 \
      int lb = r * 32;                                                         \
      size_t go = (size_t)(r + srow) * Kk + kk + schk;                         \
      gl2lds16(Ah + arow0 + go, &sAh[lb]);                                     \
      gl2lds16(Al + arow0 + go, &sAl[lb]);                                     \
      gl2lds16(Bh + brow0 + go, &sBh[lb]);                                     \
      gl2lds16(Bl + brow0 + go, &sBl[lb]);                                     \
    }                                                                          \
    __syncthreads();                                                           \
    f16x8 ah[4], al[4], bh[4], bl[4];                                          \
    _Pragma("unroll") for (int t = 0; t < 4; ++t) {                            \
      int ao = (wm * 64 + t * 16 + n16) * 32 + quad * 8;                       \
      int bo = (wn * 64 + t * 16 + n16) * 32 + quad * 8;                       \
      ah[t] = *(const f16x8*)&sAh[ao];                                         \
      al[t] = *(const f16x8*)&sAl[ao];                                         \
      bh[t] = *(const f16x8*)&sBh[bo];                                         \
      bl[t] = *(const f16x8*)&sBl[bo];                                         \
    }                                                                          \
    _Pragma("unroll") for (int ti = 0; ti < 4; ++ti)                           \
        _Pragma("unroll") for (int tj = 0; tj < 4; ++tj) {                     \
      acc[ti][tj] = __builtin_amdgcn_mfma_f32_16x16x32_f16(ah[ti], bh[tj],     \
                                                           acc[ti][tj], 0, 0, 0); \
      acc[ti][tj] = __builtin_amdgcn_mfma_f32_16x16x32_f16(ah[ti], bl[tj],     \
                                                           acc[ti][tj], 0, 0, 0); \
      acc[ti][tj] = __builtin_amdgcn_mfma_f32_16x16x32_f16(al[ti], bh[tj],     \
                                                           acc[ti][tj], 0, 0, 0); \
    }                                                                          \
  }

// Fused QKV GEMM: blockIdx.y in [0,16)=Q (RoPE epi), [16,32)=K (RoPE epi),
// [32,48)=V (plain fp32 epi).
__global__ __launch_bounds__(256) void gemm128_qkv(
    const f16* __restrict__ Xh, const f16* __restrict__ Xl,
    const f16* __restrict__ Wqh, const f16* __restrict__ Wql,
    const f16* __restrict__ Wkh, const f16* __restrict__ Wkl,
    const f16* __restrict__ Wvh, const f16* __restrict__ Wvl,
    f16* __restrict__ Qoh, f16* __restrict__ Qol,
    f16* __restrict__ Koh, f16* __restrict__ Kol,
    float* __restrict__ Vo) {
  const int sel = blockIdx.y >> 4;  // 0=Q 1=K 2=V (block-uniform)
  const f16* Bh = (sel == 0) ? Wqh : (sel == 1) ? Wkh : Wvh;
  const f16* Bl = (sel == 0) ? Wql : (sel == 1) ? Wkl : Wvl;
  GEMM128_BODY(Xh, Xl, Bh, Bl, HID, ((int)blockIdx.y & 15))
  if (sel == 2) {
    // plain fp32 epilogue into Vo [M, HID]
#pragma unroll
    for (int ti = 0; ti < 4; ++ti)
#pragma unroll
      for (int tj = 0; tj < 4; ++tj) {
        size_t row = (size_t)(im * 128 + wm * 64 + ti * 16 + quad * 4);
        size_t col = jn * 128 + wn * 64 + tj * 16 + n16;
#pragma unroll
        for (int r = 0; r < 4; ++r)
          Vo[(row + r) * HID + col] = acc[ti][tj][r];
      }
  } else {
    // fused RoPE + qscale + f16 hi/lo split, head-major [head][s][d]
    f16* Oh = sel ? Koh : Qoh;
    f16* Ol = sel ? Kol : Qol;
    const float qscale = sel ? 1.0f : 0.125f;
    const int hidx = (jn * 128 + wn * 64) >> 6;  // 0..31
    const int b = im >> 4;                       // im*128 / 2048
    const size_t obase = (size_t)(b * 32 + hidx) * Sd * 64;
    const float inv0 = expf(-0.2878231366242557f * (float)n16);
    const float inv1 = expf(-0.2878231366242557f * (float)(16 + n16));
#pragma unroll
    for (int ti = 0; ti < 4; ++ti)
#pragma unroll
      for (int r = 0; r < 4; ++r) {
        int row = im * 128 + wm * 64 + ti * 16 + quad * 4 + r;
        int s = row & (Sd - 1);
#pragma unroll
        for (int tjp = 0; tjp < 2; ++tjp) {
          float inv = tjp ? inv1 : inv0;
          float sn, cs;
          sincosf((float)s * inv, &sn, &cs);
          float x1 = acc[ti][tjp][r] * qscale;
          float x2 = acc[ti][tjp + 2][r] * qscale;
          float o1 = x1 * cs - x2 * sn;
          float o2 = x2 * cs + x1 * sn;
          size_t i1 = obase + (size_t)s * 64 + tjp * 16 + n16;
          f16 hh;
          hh = (f16)o1; Oh[i1] = hh;      Ol[i1] = (f16)(o1 - (float)hh);
          hh = (f16)o2; Oh[i1 + 32] = hh; Ol[i1 + 32] = (f16)(o2 - (float)hh);
        }
      }
  }
}

// Single-pass f16 GEMM for the output projection. Its result is never
// re-quantized, so f16 representation error (~1e-4 abs on out) is fine.
__global__ __launch_bounds__(256) void gemm128_h(const f16* __restrict__ Ah,
                                                 const f16* __restrict__ Bh,
                                                 float* __restrict__ C,
                                                 int Nn, int Kk) {
  __shared__ f16 sAh[128 * 32];
  __shared__ f16 sBh[128 * 32];
  const int tid = threadIdx.x;
  const int w = tid >> 6, lane = tid & 63;
  const int wm = w & 1, wn = w >> 1;
  const int quad = lane >> 4, n16 = lane & 15;
  const int im = blockIdx.x, jn = blockIdx.y;
  const int srow = lane >> 2;
  const int schk = (lane & 3) * 8;
  const size_t arow0 = (size_t)(im * 128) * Kk;
  const size_t brow0 = (size_t)(jn * 128) * Kk;
  f32x4 acc[4][4];
#pragma unroll
  for (int i = 0; i < 4; ++i)
#pragma unroll
    for (int j = 0; j < 4; ++j) acc[i][j] = f32x4{0.f, 0.f, 0.f, 0.f};
  for (int kk = 0; kk < Kk; kk += 32) {
    __syncthreads();
#pragma unroll
    for (int g = 0; g < 2; ++g) {
      int r = g * 64 + w * 16;
      int lb = r * 32;
      size_t go = (size_t)(r + srow) * Kk + kk + schk;
      gl2lds16(Ah + arow0 + go, &sAh[lb]);
      gl2lds16(Bh + brow0 + go, &sBh[lb]);
    }
    __syncthreads();
    f16x8 ah[4], bh[4];
#pragma unroll
    for (int t = 0; t < 4; ++t) {
      int ao = (wm * 64 + t * 16 + n16) * 32 + quad * 8;
      int bo = (wn * 64 + t * 16 + n16) * 32 + quad * 8;
      ah[t] = *(const f16x8*)&sAh[ao];
      bh[t] = *(const f16x8*)&sBh[bo];
    }
#pragma unroll
    for (int ti = 0; ti < 4; ++ti)
#pragma unroll
      for (int tj = 0; tj < 4; ++tj)
        acc[ti][tj] = __builtin_amdgcn_mfma_f32_16x16x32_f16(ah[ti], bh[tj],
                                                             acc[ti][tj], 0, 0, 0);
  }
#pragma unroll
  for (int ti = 0; ti < 4; ++ti)
#pragma unroll
    for (int tj = 0; tj < 4; ++tj) {
      size_t row = (size_t)(im * 128 + wm * 64 + ti * 16 + quad * 4);
      size_t col = jn * 128 + wn * 64 + tj * 16 + n16;
#pragma unroll
      for (int r = 0; r < 4; ++r)
        C[(row + r) * Nn + col] = acc[ti][tj][r];
    }
}

// ---------------- V transpose + split: Vt[head][d][s] -----------------------
__global__ __launch_bounds__(256) void v_split_t_kernel(const float* __restrict__ V,
                                                        f16* __restrict__ Vth,
                                                        f16* __restrict__ Vtl) {
  __shared__ float tile[64][65];
  int head = blockIdx.x;
  int st = blockIdx.y;
  int b = head >> 5, h = head & 31;
  int tid = threadIdx.x;
  int r = tid >> 2, c4 = (tid & 3) * 16;
  const float* vp = V + (((size_t)(b * Sd + st * 64 + r)) * NH + h) * 64 + c4;
#pragma unroll
  for (int i = 0; i < 16; i += 4) {
    float4 v = *(const float4*)(vp + i);
    tile[r][c4 + i] = v.x; tile[r][c4 + i + 1] = v.y;
    tile[r][c4 + i + 2] = v.z; tile[r][c4 + i + 3] = v.w;
  }
  __syncthreads();
  int d = tid >> 2, s0 = (tid & 3) * 16;
  f16x8 hv[2], lv[2];
#pragma unroll
  for (int g = 0; g < 2; ++g)
#pragma unroll
    for (int i = 0; i < 8; ++i) {
      float v = tile[s0 + g * 8 + i][d];
      f16 hh = (f16)v;
      hv[g][i] = hh;
      lv[g][i] = (f16)(v - (float)hh);
    }
  size_t outb = (size_t)head * 64 * Sd + (size_t)d * Sd + st * 64 + s0;
  *(f16x8*)(Vth + outb) = hv[0];
  *(f16x8*)(Vth + outb + 8) = hv[1];
  *(f16x8*)(Vtl + outb) = lv[0];
  *(f16x8*)(Vtl + outb + 8) = lv[1];
}

// ---------------- MFMA flash attention, 128 q-rows per block ----------------
// 4 waves x 32 q-rows; K/V tiles of 64; f16 hi/lo split on Q/K/V; P hi-only.
// True T14: barriers are lgkmcnt-only so the next tile's register prefetch
// stays in flight across the barrier and drains under compute.
__global__ __launch_bounds__(256) void attn_mfma_kernel(
    const f16* __restrict__ Qh, const f16* __restrict__ Ql,
    const f16* __restrict__ Kh, const f16* __restrict__ Kl,
    const f16* __restrict__ Vth, const f16* __restrict__ Vtl,
    float* __restrict__ O) {
  __shared__ f16 lds_kh[64 * LSTR];
  __shared__ f16 lds_kl[64 * LSTR];
  __shared__ f16 lds_vh[64 * LSTR];
  __shared__ f16 lds_vl[64 * LSTR];
  __shared__ f16 lds_ph[128 * PSTR];   // 4 waves * 32 rows (hi only)

  const int tid = threadIdx.x;
  const int wave = tid >> 6, lane = tid & 63;
  const int quad = lane >> 4, n16 = lane & 15;
  const int head = blockIdx.x;
  const int qt = 15 - blockIdx.y;        // longest blocks first
  const int b = head >> 5, h = head & 31;

  const size_t hbase = (size_t)head * Sd * 64;
  const size_t vbase = (size_t)head * 64 * Sd;
  const int qrow_w = qt * 128 + wave * 32;

  // persistent Q fragments (A-layout), 2 row-tiles of 16
  f16x8 qah[2][2], qal[2][2];
#pragma unroll
  for (int ti = 0; ti < 2; ++ti) {
    const f16* qp = Qh + hbase + (size_t)(qrow_w + ti * 16 + n16) * 64 + quad * 8;
    const f16* qp2 = Ql + hbase + (size_t)(qrow_w + ti * 16 + n16) * 64 + quad * 8;
    qah[ti][0] = *(const f16x8*)(qp);
    qah[ti][1] = *(const f16x8*)(qp + 32);
    qal[ti][0] = *(const f16x8*)(qp2);
    qal[ti][1] = *(const f16x8*)(qp2 + 32);
  }

  f32x4 acco[2][4];
#pragma unroll
  for (int ti = 0; ti < 2; ++ti)
#pragma unroll
    for (int t = 0; t < 4; ++t) acco[ti][t] = f32x4{0.f, 0.f, 0.f, 0.f};
  float mrow[2][4], lrow[2][4];
#pragma unroll
  for (int ti = 0; ti < 2; ++ti)
#pragma unroll
    for (int r = 0; r < 4; ++r) { mrow[ti][r] = -INFINITY; lrow[ti][r] = 0.f; }

  const int sr = tid >> 2, ss = (tid & 3) * 16;
  const int nkt = 2 * qt + 2;

  // staging source pointers (advance by constants per kt)
  const f16* pk  = Kh  + hbase + (size_t)sr * 64 + ss;
  const f16* pkl = Kl  + hbase + (size_t)sr * 64 + ss;
  const f16* pv  = Vth + vbase + (size_t)sr * Sd + ss;
  const f16* pvl = Vtl + vbase + (size_t)sr * Sd + ss;

  f16x8 r0, r1, r2, r3, r4, r5, r6, r7;
#define ISSUE_KV(ktv) {                                                        \
    const f16* gk  = pk  + (size_t)(ktv) * (64 * 64);                          \
    const f16* gkl = pkl + (size_t)(ktv) * (64 * 64);                          \
    const f16* gv  = pv  + (ktv) * 64;                                         \
    const f16* gvl = pvl + (ktv) * 64;                                         \
    r0 = *(const f16x8*)(gk);      r1 = *(const f16x8*)(gk + 8);               \
    r2 = *(const f16x8*)(gkl);     r3 = *(const f16x8*)(gkl + 8);              \
    r4 = *(const f16x8*)(gv);      r5 = *(const f16x8*)(gv + 8);               \
    r6 = *(const f16x8*)(gvl);     r7 = *(const f16x8*)(gvl + 8); }

  // lgkmcnt-only barrier: does NOT drain vmcnt, so register-destined global
  // prefetch flies across it (wave-private; no cross-wave hazard).
#define LDS_BARRIER() __asm__ volatile("s_waitcnt lgkmcnt(0)\n\ts_barrier" ::: "memory")

  ISSUE_KV(0);

  for (int kt = 0; kt < nkt; ++kt) {
    LDS_BARRIER();   // prev iteration's LDS reads done before overwrite
    {
      int la = sr * LSTR + ss;
      *(f16x8*)&lds_kh[la] = r0; *(f16x8*)&lds_kh[la + 8] = r1;
      *(f16x8*)&lds_kl[la] = r2; *(f16x8*)&lds_kl[la + 8] = r3;
      *(f16x8*)&lds_vh[la] = r4; *(f16x8*)&lds_vh[la + 8] = r5;
      *(f16x8*)&lds_vl[la] = r6; *(f16x8*)&lds_vl[la + 8] = r7;
    }
    if (kt + 1 < nkt) ISSUE_KV(kt + 1);   // fly under this tile's compute
    LDS_BARRIER();   // K/V writes visible; prefetch stays in flight

    if (kt * 64 > qrow_w + 31) continue;  // fully-masked for this wave

    // S = Q*K^T: 32 q-rows x 64 k-cols per wave
    f32x4 sacc[2][4];
#pragma unroll
    for (int ti = 0; ti < 2; ++ti)
#pragma unroll
      for (int t = 0; t < 4; ++t) sacc[ti][t] = f32x4{0.f, 0.f, 0.f, 0.f};
#pragma unroll
    for (int t = 0; t < 4; ++t) {
      int off = (t * 16 + n16) * LSTR + quad * 8;
      f16x8 kb0h = *(const f16x8*)&lds_kh[off];
      f16x8 kb1h = *(const f16x8*)&lds_kh[off + 32];
      f16x8 kb0l = *(const f16x8*)&lds_kl[off];
      f16x8 kb1l = *(const f16x8*)&lds_kl[off + 32];
#pragma unroll
      for (int ti = 0; ti < 2; ++ti) {
        sacc[ti][t] = __builtin_amdgcn_mfma_f32_16x16x32_f16(qah[ti][0], kb0h, sacc[ti][t], 0, 0, 0);
        sacc[ti][t] = __builtin_amdgcn_mfma_f32_16x16x32_f16(qah[ti][1], kb1h, sacc[ti][t], 0, 0, 0);
        sacc[ti][t] = __builtin_amdgcn_mfma_f32_16x16x32_f16(qah[ti][0], kb0l, sacc[ti][t], 0, 0, 0);
        sacc[ti][t] = __builtin_amdgcn_mfma_f32_16x16x32_f16(qah[ti][1], kb1l, sacc[ti][t], 0, 0, 0);
        sacc[ti][t] = __builtin_amdgcn_mfma_f32_16x16x32_f16(qal[ti][0], kb0h, sacc[ti][t], 0, 0, 0);
        sacc[ti][t] = __builtin_amdgcn_mfma_f32_16x16x32_f16(qal[ti][1], kb1h, sacc[ti][t], 0, 0, 0);
      }
    }

    if (kt * 64 + 63 > qrow_w) {  // partial mask
#pragma unroll
      for (int ti = 0; ti < 2; ++ti)
#pragma unroll
        for (int t = 0; t < 4; ++t)
#pragma unroll
          for (int r = 0; r < 4; ++r) {
            int kc = kt * 64 + t * 16 + n16;
            int qr = qrow_w + ti * 16 + quad * 4 + r;
            if (kc > qr) sacc[ti][t][r] = -INFINITY;
          }
    }

    // online softmax per row-tile (P stored hi-only)
#pragma unroll
    for (int ti = 0; ti < 2; ++ti) {
      float mt[4];
#pragma unroll
      for (int r = 0; r < 4; ++r)
        mt[r] = fmaxf(fmaxf(sacc[ti][0][r], sacc[ti][1][r]),
                      fmaxf(sacc[ti][2][r], sacc[ti][3][r]));
#pragma unroll
      for (int i = 1; i < 16; i <<= 1)
#pragma unroll
        for (int r = 0; r < 4; ++r)
          mt[r] = fmaxf(mt[r], __shfl_xor(mt[r], i));
      float alpha[4], psum[4];
#pragma unroll
      for (int r = 0; r < 4; ++r) {
        float mn = fmaxf(mrow[ti][r], mt[r]);
        alpha[r] = __expf(mrow[ti][r] - mn);
        mrow[ti][r] = mn;
        psum[r] = 0.f;
      }
#pragma unroll
      for (int t = 0; t < 4; ++t)
#pragma unroll
        for (int r = 0; r < 4; ++r) {
          float p = __expf(sacc[ti][t][r] - mrow[ti][r]);
          psum[r] += p;
          int addr = (wave * 32 + ti * 16 + quad * 4 + r) * PSTR + t * 16 + n16;
          lds_ph[addr] = (f16)p;
        }
#pragma unroll
      for (int i = 1; i < 16; i <<= 1)
#pragma unroll
        for (int r = 0; r < 4; ++r)
          psum[r] += __shfl_xor(psum[r], i);
#pragma unroll
      for (int r = 0; r < 4; ++r) lrow[ti][r] = lrow[ti][r] * alpha[r] + psum[r];
#pragma unroll
      for (int t = 0; t < 4; ++t)
#pragma unroll
        for (int r = 0; r < 4; ++r) acco[ti][t][r] *= alpha[r];
    }

    __asm__ volatile("s_waitcnt lgkmcnt(0)" ::: "memory");

    // O += P * V (P hi-only: 4 MFMA per fragment pair)
    f16x8 pa0h[2], pa1h[2];
#pragma unroll
    for (int ti = 0; ti < 2; ++ti) {
      int pbase = (wave * 32 + ti * 16 + n16) * PSTR + quad * 8;
      pa0h[ti] = *(const f16x8*)&lds_ph[pbase];
      pa1h[ti] = *(const f16x8*)&lds_ph[pbase + 32];
    }
#pragma unroll
    for (int t = 0; t < 4; ++t) {
      int off = (t * 16 + n16) * LSTR + quad * 8;
      f16x8 vb0h = *(const f16x8*)&lds_vh[off];
      f16x8 vb1h = *(const f16x8*)&lds_vh[off + 32];
      f16x8 vb0l = *(const f16x8*)&lds_vl[off];
      f16x8 vb1l = *(const f16x8*)&lds_vl[off + 32];
#pragma unroll
      for (int ti = 0; ti < 2; ++ti) {
        acco[ti][t] = __builtin_amdgcn_mfma_f32_16x16x32_f16(pa0h[ti], vb0h, acco[ti][t], 0, 0, 0);
        acco[ti][t] = __builtin_amdgcn_mfma_f32_16x16x32_f16(pa1h[ti], vb1h, acco[ti][t], 0, 0, 0);
        acco[ti][t] = __builtin_amdgcn_mfma_f32_16x16x32_f16(pa0h[ti], vb0l, acco[ti][t], 0, 0, 0);
        acco[ti][t] = __builtin_amdgcn_mfma_f32_16x16x32_f16(pa1h[ti], vb1l, acco[ti][t], 0, 0, 0);
      }
    }
  }
#undef ISSUE_KV
#undef LDS_BARRIER

  // epilogue: O in [b,s,h,d] fp32
#pragma unroll
  for (int ti = 0; ti < 2; ++ti) {
#pragma unroll
    for (int r = 0; r < 4; ++r) {
      float rl = 1.f / lrow[ti][r];
      int qr = qrow_w + ti * 16 + quad * 4 + r;
#pragma unroll
      for (int t = 0; t < 4; ++t)
        O[(((size_t)(b * Sd + qr)) * NH + h) * 64 + t * 16 + n16] = acco[ti][t][r] * rl;
    }
  }
}

// ---------------- launch ----------------------------------------------------
extern "C" void kernel_launch(void* const* d_in, const int* in_sizes, int n_in,
                              void* d_out, int out_size, void* d_ws, size_t ws_size,
                              hipStream_t stream) {
  (void)in_sizes; (void)n_in; (void)out_size; (void)ws_size;
  const float* x  = (const float*)d_in[0];
  const float* Wq = (const float*)d_in[1];
  const float* Wk = (const float*)d_in[2];
  const float* Wv = (const float*)d_in[3];
  const float* Wo = (const float*)d_in[4];
  float* out = (float*)d_out;

  const size_t NX = (size_t)Md * HID;   // 8,388,608
  const size_t NW = (size_t)HID * HID;  // 4,194,304

  char* w = (char*)d_ws;
  size_t off = 0;
  auto alloc = [&](size_t bytes) { void* p = w + off; off += (bytes + 255) & ~(size_t)255; return p; };
  f16* xh  = (f16*)alloc(NX * 2);
  f16* xl  = (f16*)alloc(NX * 2);
  f16* wqh = (f16*)alloc(NW * 2);
  f16* wql = (f16*)alloc(NW * 2);
  f16* wkh = (f16*)alloc(NW * 2);
  f16* wkl = (f16*)alloc(NW * 2);
  f16* wvh = (f16*)alloc(NW * 2);
  f16* wvl = (f16*)alloc(NW * 2);
  f16* woh = (f16*)alloc(NW * 2);
  f16* wol = (f16*)alloc(NW * 2);
  float* vb = (float*)alloc(NX * 4);
  f16* qhs = (f16*)alloc(NX * 2);
  f16* qls = (f16*)alloc(NX * 2);
  f16* khs = (f16*)alloc(NX * 2);
  f16* kls = (f16*)alloc(NX * 2);
  // aliases (dead-after analysis):
  f16* vth = xh;            // x splits dead after QKV gemm; vth/vtl live for attn
  f16* vtl = xl;
  float* ob = (float*)wqh;  // wq/wk splits dead after QKV gemm (4*NW*2 = NX*4 B)
  f16* oh = qhs;            // q splits dead after attn
  f16* ol = qls;

  const int nx4 = (int)(NX / 4);
  const int nw4 = (int)(NW / 4);
  quant_fp4_split_kernel<<<nx4 / 256, 256, 0, stream>>>(x, xh, xl, nx4);
  quant_fp4_split_kernel<<<nw4 / 256, 256, 0, stream>>>(Wq, wqh, wql, nw4);
  quant_fp4_split_kernel<<<nw4 / 256, 256, 0, stream>>>(Wk, wkh, wkl, nw4);
  quant_fp4_split_kernel<<<nw4 / 256, 256, 0, stream>>>(Wv, wvh, wvl, nw4);
  quant_fp4_split_kernel<<<nw4 / 256, 256, 0, stream>>>(Wo, woh, wol, nw4);

  // fused Q/K/V projection GEMM: grid (32, 48)
  gemm128_qkv<<<dim3(Md / 128, 48), 256, 0, stream>>>(
      xh, xl, wqh, wql, wkh, wkl, wvh, wvl, qhs, qls, khs, kls, vb);

  v_split_t_kernel<<<dim3(64, 32), 256, 0, stream>>>(vb, vth, vtl);

  attn_mfma_kernel<<<dim3(64, 16), 256, 0, stream>>>(qhs, qls, khs, kls, vth, vtl, ob);

  quant_fp4_split_kernel<<<nx4 / 256, 256, 0, stream>>>(ob, oh, ol, nx4);
  // single-pass f16 output projection (result never re-quantized)
  gemm128_h<<<dim3(Md / 128, HID / 128), 256, 0, stream>>>(oh, woh, out, HID, HID);
}